// Round 3
// baseline (309.911 us; speedup 1.0000x reference)
//
#include <hip/hip_runtime.h>

#define Vv 30
#define Tt 8192
#define Kk 5
#define Ll 512
#define Bb 32
#define NVK (Vv * Kk)      // 150 real rows
#define ZROW NVK           // row 150 = zeros (for out-of-range neighbors)
#define NROWS (NVK + 1)    // 151 rows
#define NC (Tt / 4)        // 2048 chunks of 4 t-values
#define MARGIN 1e-3f       // prune margin >> fp32 rounding (~5e-7), << ub sd (0.127)

__device__ inline float4 add4(float4 a, float4 b) {
    return make_float4(a.x + b.x, a.y + b.y, a.z + b.z, a.w + b.w);
}

// ---------------------------------------------------------------------------
// Kernel 1: transpose conv_w (T,V,K) -> wt[vk][t] with bias folded into k==2
// rows, zero row, AND per-4-chunk max table cm[row][c].
// Grid: T/32 = 256 blocks x 256 threads.
// ---------------------------------------------------------------------------
__global__ __launch_bounds__(256) void prep_w(
    const float* __restrict__ conv_w,
    const float* __restrict__ conv_b,
    float* __restrict__ wt,
    float* __restrict__ cm)
{
    const int TILE = 32;
    __shared__ float tile[TILE * NVK];   // 19.2 KB

    const int t0 = blockIdx.x * TILE;

    for (int i = threadIdx.x; i < TILE * NVK; i += 256)
        tile[i] = conv_w[t0 * NVK + i];
    __syncthreads();

    // Transposed + bias-folded write.
    for (int i = threadIdx.x; i < NVK * TILE; i += 256) {
        const int vk = i >> 5;
        const int tl = i & 31;
        float v = tile[tl * NVK + vk];
        const int k = vk - (vk / Kk) * Kk;
        if (k == 2) v += conv_b[t0 + tl];
        wt[vk * Tt + t0 + tl] = v;
    }
    if (threadIdx.x < TILE)
        wt[ZROW * Tt + t0 + threadIdx.x] = 0.0f;

    // chunkmax: 8 chunks (of 4 t) per row per block, all NROWS rows.
    for (int idx = threadIdx.x; idx < NROWS * 8; idx += 256) {
        const int row = idx >> 3;
        const int cj  = idx & 7;
        float m;
        if (row == ZROW) {
            m = 0.0f;
        } else {
            const int k = row - (row / Kk) * Kk;
            m = -1e30f;
#pragma unroll
            for (int q = 0; q < 4; ++q) {
                const int tl = cj * 4 + q;
                float v = tile[tl * NVK + row];
                if (k == 2) v += conv_b[t0 + tl];
                m = fmaxf(m, v);
            }
        }
        cm[row * NC + (t0 >> 2) + cj] = m;
    }
}

// ---------------------------------------------------------------------------
// Kernel 2: pruned argmax. Block per position (16384 x 256).
// Phase A: upper bounds for all 2048 chunks from L2-resident 1.24 MB table.
// Phase B: exact eval only of chunks with ub >= best0 - margin (~0.3%).
// ---------------------------------------------------------------------------
__global__ __launch_bounds__(256) void conv_argmax2(
    const int* __restrict__ seq,
    const float* __restrict__ wt,
    const float* __restrict__ cm,
    int* __restrict__ out)
{
    const int pos = blockIdx.x;
    const int b = pos >> 9;
    const int l = pos & (Ll - 1);

    int rows[Kk];
#pragma unroll
    for (int k = 0; k < Kk; ++k) {
        const int lp = l + k - Kk / 2;
        rows[k] = (lp >= 0 && lp < Ll) ? (seq[b * Ll + lp] * Kk + k) : ZROW;
    }

    const float4* __restrict__ c0 = (const float4*)(cm + rows[0] * NC);
    const float4* __restrict__ c1 = (const float4*)(cm + rows[1] * NC);
    const float4* __restrict__ c2 = (const float4*)(cm + rows[2] * NC);
    const float4* __restrict__ c3 = (const float4*)(cm + rows[3] * NC);
    const float4* __restrict__ c4 = (const float4*)(cm + rows[4] * NC);
    const float4* __restrict__ r0 = (const float4*)(wt + (size_t)rows[0] * Tt);
    const float4* __restrict__ r1 = (const float4*)(wt + (size_t)rows[1] * Tt);
    const float4* __restrict__ r2 = (const float4*)(wt + (size_t)rows[2] * Tt);
    const float4* __restrict__ r3 = (const float4*)(wt + (size_t)rows[3] * Tt);
    const float4* __restrict__ r4 = (const float4*)(wt + (size_t)rows[4] * Tt);

    const int tid = threadIdx.x;

    // ---- Phase A: ub for chunks [4*tid..4*tid+3] and [1024+4*tid..+3] ----
    // Same add tree as exact eval so rounding stays within a few ulps.
    const float4 uA = add4(add4(add4(c0[tid],       c1[tid]),
                                add4(c2[tid],       c3[tid])),       c4[tid]);
    const float4 uB = add4(add4(add4(c0[256 + tid], c1[256 + tid]),
                                add4(c2[256 + tid], c3[256 + tid])), c4[256 + tid]);

    const float ub8[8] = {uA.x, uA.y, uA.z, uA.w, uB.x, uB.y, uB.z, uB.w};

    // Thread-local max ub + its chunk (static unroll; no runtime array index).
    float mu = ub8[0];
    int   mc = tid * 4;
#pragma unroll
    for (int j = 1; j < 8; ++j) {
        const int c = (j < 4) ? (tid * 4 + j) : (1024 + tid * 4 + (j - 4));
        if (ub8[j] > mu) { mu = ub8[j]; mc = c; }
    }

    // Block reduce -> chunk with global max ub.
#pragma unroll
    for (int off = 32; off >= 1; off >>= 1) {
        const float om = __shfl_down(mu, off);
        const int   oc = __shfl_down(mc, off);
        if (om > mu) { mu = om; mc = oc; }
    }
    __shared__ float smu[4];
    __shared__ int   smc[4];
    __shared__ int   scstar;
    if ((tid & 63) == 0) { smu[tid >> 6] = mu; smc[tid >> 6] = mc; }
    __syncthreads();
    if (tid == 0) {
#pragma unroll
        for (int w = 1; w < 4; ++w)
            if (smu[w] > mu) { mu = smu[w]; mc = smc[w]; }
        scstar = mc;
    }
    __syncthreads();
    const int cstar = scstar;

    // Exact eval of c* (uniform across block, broadcast loads).
    const float4 e = add4(add4(add4(r0[cstar], r1[cstar]),
                               add4(r2[cstar], r3[cstar])), r4[cstar]);
    float bv = e.x;  int bt = cstar * 4;
    if (e.y > bv) { bv = e.y; bt = cstar * 4 + 1; }
    if (e.z > bv) { bv = e.z; bt = cstar * 4 + 2; }
    if (e.w > bv) { bv = e.w; bt = cstar * 4 + 3; }

    const float thresh = bv - MARGIN;

    // ---- Phase B: exact eval of surviving chunks (~0.3%) ----
#pragma unroll
    for (int j = 0; j < 8; ++j) {
        const int c = (j < 4) ? (tid * 4 + j) : (1024 + tid * 4 + (j - 4));
        const float u = ub8[j];
        if (u >= thresh) {
            const float4 e2 = add4(add4(add4(r0[c], r1[c]),
                                        add4(r2[c], r3[c])), r4[c]);
            const float es0 = e2.x, es1 = e2.y, es2 = e2.z, es3 = e2.w;
            int t = c * 4;
            if (es0 > bv || (es0 == bv && t < bt))         { bv = es0; bt = t; }
            t = c * 4 + 1;
            if (es1 > bv || (es1 == bv && t < bt))         { bv = es1; bt = t; }
            t = c * 4 + 2;
            if (es2 > bv || (es2 == bv && t < bt))         { bv = es2; bt = t; }
            t = c * 4 + 3;
            if (es3 > bv || (es3 == bv && t < bt))         { bv = es3; bt = t; }
        }
    }

    // ---- Final block argmax reduce (smallest t on ties) ----
#pragma unroll
    for (int off = 32; off >= 1; off >>= 1) {
        const float ov = __shfl_down(bv, off);
        const int   ot = __shfl_down(bt, off);
        if (ov > bv || (ov == bv && ot < bt)) { bv = ov; bt = ot; }
    }
    __shared__ float sv[4];
    __shared__ int   si[4];
    if ((tid & 63) == 0) { sv[tid >> 6] = bv; si[tid >> 6] = bt; }
    __syncthreads();
    if (tid == 0) {
#pragma unroll
        for (int w = 1; w < 4; ++w)
            if (sv[w] > bv || (sv[w] == bv && si[w] < bt)) { bv = sv[w]; bt = si[w]; }
        out[pos] = bt;
    }
}

// ---------------------------------------------------------------------------
extern "C" void kernel_launch(void* const* d_in, const int* in_sizes, int n_in,
                              void* d_out, int out_size, void* d_ws, size_t ws_size,
                              hipStream_t stream)
{
    const int*   seq    = (const int*)d_in[0];     // (B, L) int32
    const float* conv_w = (const float*)d_in[1];   // (T, V, K) f32
    const float* conv_b = (const float*)d_in[2];   // (T,) f32
    int*         out    = (int*)d_out;             // (B, L) int32
    float*       wt     = (float*)d_ws;                         // 151*8192 f32
    float*       cm     = (float*)d_ws + (size_t)NROWS * Tt;    // 151*2048 f32

    prep_w<<<Tt / 32, 256, 0, stream>>>(conv_w, conv_b, wt, cm);
    conv_argmax2<<<Bb * Ll, 256, 0, stream>>>(seq, wt, cm, out);
}

// Round 4
// 129.500 us; speedup vs baseline: 2.3931x; 2.3931x over previous
//
#include <hip/hip_runtime.h>

#define Vv 30
#define Tt 8192
#define Kk 5
#define Ll 512
#define Bb 32
#define NVK 150            // real rows (v*5+k)
#define ZROW 150           // zero row for out-of-range taps
#define NROWS 151
#define TPOS (Bb * Ll)     // 16384 positions
#define PG 32              // position groups
#define PPB (TPOS / PG)    // 512 positions per block
#define PPT (PPB / 256)    // 2 positions per thread
#define TR 16              // t-ranges (partials combined in kernel 3)
#define TW (Tt / TR)       // 512 t per range
#define TILE_T 64          // t-values per LDS tile
#define NTILE (TW / TILE_T)
#define LSTRIDE 68         // floats per LDS row: 64 + 4 pad (17 granules, odd -> bank spread)

// ---------------------------------------------------------------------------
// Kernel 1: transpose conv_w (T,V,K) -> wt[vk][t], fold bias into k==2 rows,
// write zero row. Grid: 256 blocks x 256 threads.
// ---------------------------------------------------------------------------
__global__ __launch_bounds__(256) void prep_w(
    const float* __restrict__ conv_w,
    const float* __restrict__ conv_b,
    float* __restrict__ wt)
{
    const int TILE = 32;
    __shared__ float tile[TILE * NVK];   // 19.2 KB

    const int t0 = blockIdx.x * TILE;

    for (int i = threadIdx.x; i < TILE * NVK; i += 256)
        tile[i] = conv_w[t0 * NVK + i];
    __syncthreads();

    for (int i = threadIdx.x; i < NVK * TILE; i += 256) {
        const int vk = i >> 5;
        const int tl = i & 31;
        float v = tile[tl * NVK + vk];
        const int k = vk - (vk / Kk) * Kk;
        if (k == 2) v += conv_b[t0 + tl];
        wt[vk * Tt + t0 + tl] = v;
    }
    if (threadIdx.x < TILE)
        wt[ZROW * Tt + t0 + threadIdx.x] = 0.0f;
}

// ---------------------------------------------------------------------------
// Kernel 2: tiled gather-sum + per-range argmax.
// Grid: PG*TR = 512 blocks x 256 threads. Block (pg, tr) handles 512
// positions over 512 t-values, staging [151 x 64] weight tiles in LDS.
// ---------------------------------------------------------------------------
__global__ __launch_bounds__(256) void conv_argmax3(
    const int* __restrict__ seq,
    const float* __restrict__ wt,
    float2* __restrict__ partials)
{
    __shared__ float tile[NROWS * LSTRIDE];          // 41 KB
    float4* __restrict__ tile4 = (float4*)tile;

    const int bid = blockIdx.x;
    const int pg  = bid & (PG - 1);    // same-tr blocks spread across XCDs
    const int tr  = bid >> 5;
    const int tid = threadIdx.x;

    // Row offsets (in float4 granules) for this thread's PPT positions.
    int f4off[PPT][Kk];
#pragma unroll
    for (int j = 0; j < PPT; ++j) {
        const int pos = pg * PPB + j * 256 + tid;
        const int b = pos >> 9;
        const int l = pos & (Ll - 1);
#pragma unroll
        for (int k = 0; k < Kk; ++k) {
            const int lp = l + k - 2;
            const int row = (lp >= 0 && lp < Ll) ? (seq[b * Ll + lp] * Kk + k) : ZROW;
            f4off[j][k] = row * (LSTRIDE / 4);   // 17 granules per LDS row
        }
    }

    float bv[PPT];
    int   bt[PPT];
#pragma unroll
    for (int j = 0; j < PPT; ++j) { bv[j] = -1e30f; bt[j] = 0; }

    const int t_base = tr * TW;
    const float4* __restrict__ wsrc = (const float4*)wt;   // row stride Tt/4

    for (int tl = 0; tl < NTILE; ++tl) {
        const int t0 = t_base + tl * TILE_T;

        __syncthreads();   // previous tile's compute done before overwrite
        // Stage 151 x 64 floats: 2416 float4 loads, coalesced 256B/row.
        for (int i = tid; i < NROWS * (TILE_T / 4); i += 256) {
            const int row = i >> 4;
            const int col = i & 15;
            tile4[row * (LSTRIDE / 4) + col] =
                wsrc[row * (Tt / 4) + (t0 >> 2) + col];
        }
        __syncthreads();

#pragma unroll 2
        for (int c4 = 0; c4 < TILE_T / 4; ++c4) {
            const int tg = t0 + c4 * 4;
#pragma unroll
            for (int j = 0; j < PPT; ++j) {
                const float4 a = tile4[f4off[j][0] + c4];
                const float4 c = tile4[f4off[j][1] + c4];
                const float4 d = tile4[f4off[j][2] + c4];
                const float4 e = tile4[f4off[j][3] + c4];
                const float4 f = tile4[f4off[j][4] + c4];
                // Same add tree as round 1 (bit-identical sums).
                const float s0 = ((a.x + c.x) + (d.x + e.x)) + f.x;
                const float s1 = ((a.y + c.y) + (d.y + e.y)) + f.y;
                const float s2 = ((a.z + c.z) + (d.z + e.z)) + f.z;
                const float s3 = ((a.w + c.w) + (d.w + e.w)) + f.w;
                if (s0 > bv[j]) { bv[j] = s0; bt[j] = tg; }
                if (s1 > bv[j]) { bv[j] = s1; bt[j] = tg + 1; }
                if (s2 > bv[j]) { bv[j] = s2; bt[j] = tg + 2; }
                if (s3 > bv[j]) { bv[j] = s3; bt[j] = tg + 3; }
            }
        }
    }

    // Per-(position, range) partial: [pos][tr] layout for coalesced combine.
#pragma unroll
    for (int j = 0; j < PPT; ++j) {
        const int pos = pg * PPB + j * 256 + tid;
        partials[pos * TR + tr] = make_float2(bv[j], __int_as_float(bt[j]));
    }
}

// ---------------------------------------------------------------------------
// Kernel 3: combine TR partials per position (first-max tie-break).
// Grid: 64 blocks x 256 threads.
// ---------------------------------------------------------------------------
__global__ __launch_bounds__(256) void combine(
    const float2* __restrict__ partials,
    int* __restrict__ out)
{
    const int pos = blockIdx.x * 256 + threadIdx.x;
    float bv = -1e30f;
    int   bt = 0;
#pragma unroll
    for (int tr = 0; tr < TR; ++tr) {
        const float2 p = partials[pos * TR + tr];
        const int t = __float_as_int(p.y);
        if (p.x > bv || (p.x == bv && t < bt)) { bv = p.x; bt = t; }
    }
    out[pos] = bt;
}

// ---------------------------------------------------------------------------
extern "C" void kernel_launch(void* const* d_in, const int* in_sizes, int n_in,
                              void* d_out, int out_size, void* d_ws, size_t ws_size,
                              hipStream_t stream)
{
    const int*   seq    = (const int*)d_in[0];     // (B, L) int32
    const float* conv_w = (const float*)d_in[1];   // (T, V, K) f32
    const float* conv_b = (const float*)d_in[2];   // (T,) f32
    int*         out    = (int*)d_out;             // (B, L) int32
    float*       wt     = (float*)d_ws;                            // 151*8192 f32
    float2*      part   = (float2*)((float*)d_ws + (size_t)NROWS * Tt);  // 16384*16 float2

    prep_w<<<Tt / 32, 256, 0, stream>>>(conv_w, conv_b, wt);
    conv_argmax3<<<PG * TR, 256, 0, stream>>>(seq, wt, part);
    combine<<<TPOS / 256, 256, 0, stream>>>(part, out);
}